// Round 2
// baseline (1016.631 us; speedup 1.0000x reference)
//
#include <hip/hip_runtime.h>
#include <hip/hip_bf16.h>

using bf16 = __hip_bfloat16;
__device__ __forceinline__ float tof(bf16 x) { return __bfloat162float(x); }
__device__ __forceinline__ float sigm(float x) { return 1.f / (1.f + __expf(-x)); }
__device__ __forceinline__ float tanh_fast(float x) {
  float e2 = __expf(2.f * x);
  return 1.f - 2.f / (e2 + 1.f);
}

#define B_ 32
#define V_ 512
#define T_ 12
#define CH_ 16
#define EPS_ 0.3f

// ---- workspace layout (float elements) ----
constexpr size_t OFF_TWC  = 0;          // 512
constexpr size_t OFF_TWS  = 512;        // 512
constexpr size_t OFF_C    = 1024;       // 480  (cos-folded lin_W [20][24])
constexpr size_t OFF_S    = 1504;       // 480  (sin-folded lin_W)
constexpr size_t OFF_WEFF = 1984;       // 6144 [8][3][16][16]
constexpr size_t OFF_R    = 8128;       // [32][512][20]
constexpr size_t OFF_I    = 335808;     // [32][512][20]
constexpr size_t OFF_G    = 663488;     // [32][512][64]: 0..19 iff, 20..39 Am, 40..59 S
constexpr size_t OFF_ADJ  = 1712064;    // [512][512]
constexpr size_t OFF_ADJ2 = 1974208;    // [512][512]
constexpr size_t OFF_SKIP = 2236352;    // [32][16][512]
constexpr size_t OFF_X0   = 2498496;    // [32][13][16][512]
constexpr size_t OFF_X1   = 5906368;
constexpr size_t OFF_U    = 9314240;
constexpr size_t OFF_Y    = 12722112;   // [6144][1024]
constexpr size_t OFF_FLAG = 19013568;   // 8 (flag[0]: 1.0 = inputs are fp32)
constexpr size_t OFF_CIN  = 19013576;   // converted fp32 inputs, 445952 floats
constexpr size_t WS_TOTAL = 19459584;   // ~77.8 MB

// ---------- dtype detection: bf16-interpret first 4096 halfwords of input ----------
__global__ __launch_bounds__(256) void k_detect(const void* __restrict__ in0,
                                                float* __restrict__ flag) {
  __shared__ int cnt;
  if (threadIdx.x == 0) cnt = 0;
  __syncthreads();
  const unsigned short* u = (const unsigned short*)in0;
  int bad = 0;
  for (int i = threadIdx.x; i < 4096; i += 256) {
    int e = (u[i] >> 7) & 0xFF;
    if (e == 255 || (e != 0 && (e < 87 || e > 167))) bad++;
  }
  atomicAdd(&cnt, bad);
  __syncthreads();
  if (threadIdx.x == 0) flag[0] = (cnt > 200) ? 1.f : 0.f;
}

// ---------- convert one input to fp32 per flag ----------
__global__ __launch_bounds__(256) void k_conv(const void* __restrict__ src,
                                              float* __restrict__ dst, int n,
                                              const float* __restrict__ flag) {
  int i = blockIdx.x * 256 + threadIdx.x;
  if (i >= n) return;
  if (flag[0] > 0.5f) dst[i] = ((const float*)src)[i];
  else dst[i] = tof(((const bf16*)src)[i]);
}

// ---------- precompute: twiddles, folded-FFT matrices, effective gconv weights ----------
__global__ __launch_bounds__(256) void k_pre(const float* __restrict__ linW,
                                             const float* __restrict__ gconvW,
                                             float* __restrict__ ws) {
  int idx = blockIdx.x * 256 + threadIdx.x;
  const float TWO_PI = 6.2831853071795864769f;
  if (idx < 512) {
    float ang = TWO_PI * (float)idx / 512.f;
    ws[OFF_TWC + idx] = cosf(ang);
    ws[OFF_TWS + idx] = sinf(ang);
  } else if (idx < 992) {
    int e = idx - 512, d = e / 24, n = e % 24;
    float c = 0.f, s = 0.f;
    for (int k = 0; k < 24; ++k) {
      int j = (k * n) % 24;
      float ang = TWO_PI * (float)j / 24.f;
      float w = linW[d * 24 + k];
      c += w * cosf(ang);
      s -= w * sinf(ang);
    }
    ws[OFF_C + e] = c;
    ws[OFF_S + e] = s;
  } else if (idx < 992 + 2048) {
    int e = idx - 992, i = e >> 8, co = (e >> 4) & 15, ci = e & 15;
    size_t base = (size_t)(i * 16 + co) * 64 + ci;
    float W0 = gconvW[base];        // xL
    float W1 = gconvW[base + 16];   // xLL
    float W2 = gconvW[base + 32];   // xH
    float W3 = gconvW[base + 48];   // xHH
    size_t o = OFF_WEFF + (size_t)i * 768 + co * 16 + ci;
    ws[o]       = EPS_ * (W0 + W2) + EPS_ * EPS_ * (W1 + W3);  // coeff of u
    ws[o + 256] = (W0 - W2) + 2.f * EPS_ * (W1 - W3);          // coeff of u*A
    ws[o + 512] = W1 + W3;                                     // coeff of u*A^2
  }
}

// ---------- FFT(24) folded into lin_W ----------
__global__ __launch_bounds__(256) void k_fft(const float* __restrict__ in,
                                             const float* __restrict__ linb,
                                             const float* __restrict__ ws,
                                             float* __restrict__ Rw, float* __restrict__ Iw,
                                             float* __restrict__ G) {
  __shared__ float Cl[480], Sl[480], lb[20];
  int tid = threadIdx.x;
  for (int e = tid; e < 480; e += 256) { Cl[e] = ws[OFF_C + e]; Sl[e] = ws[OFF_S + e]; }
  if (tid < 20) lb[tid] = linb[tid];
  __syncthreads();
  int gid = blockIdx.x * 256 + tid;
  int b = gid >> 9, v = gid & 511;
  float xr[24];
#pragma unroll
  for (int t = 0; t < 12; ++t) {
    size_t ib = (((size_t)t * 32 + b) * 512 + v) * 2;
    xr[2 * t] = in[ib];
    xr[2 * t + 1] = in[ib + 1];
  }
  size_t gbv = (size_t)b * 512 + v;
  for (int d = 0; d < 20; ++d) {
    float R = lb[d], I = lb[d];
#pragma unroll
    for (int n = 0; n < 24; ++n) {
      R = fmaf(xr[n], Cl[d * 24 + n], R);
      I = fmaf(xr[n], Sl[d * 24 + n], I);
    }
    Rw[gbv * 20 + d] = R;
    Iw[gbv * 20 + d] = I;
    G[gbv * 64 + 20 + d] = sqrtf(R * R + I * I);
    G[gbv * 64 + 40 + d] = atanf(R / (I + 1e-4f));
  }
}

// ---------- irfft(n=512) along v, block per (b,d) ----------
__global__ __launch_bounds__(256) void k_irfft(const float* __restrict__ Rw,
                                               const float* __restrict__ Iw,
                                               const float* __restrict__ ws,
                                               float* __restrict__ G) {
  __shared__ float Rk[257], Ik[257], twc[512], tws[512];
  int blk = blockIdx.x;
  int b = blk / 20, d = blk % 20;
  int tid = threadIdx.x;
  for (int e = tid; e < 512; e += 256) { twc[e] = ws[OFF_TWC + e]; tws[e] = ws[OFF_TWS + e]; }
  for (int k = tid; k < 257; k += 256) {
    float ck = (k == 0 || k == 256) ? 1.f : 2.f;
    Rk[k] = Rw[((size_t)b * 512 + k) * 20 + d] * ck;
    Ik[k] = Iw[((size_t)b * 512 + k) * 20 + d] * ck;
  }
  __syncthreads();
#pragma unroll
  for (int s = 0; s < 2; ++s) {
    int m = tid + s * 256;
    float acc = 0.f;
    for (int k = 0; k < 257; ++k) {
      int j = (k * m) & 511;
      acc += Rk[k] * twc[j] - Ik[k] * tws[j];
    }
    G[((size_t)b * 512 + m) * 64 + d] = acc * (1.f / 512.f);
  }
}

// ---------- adj[v][w] = sigmoid(mean_b sigmoid((G.Wc + bsum)/3)) ----------
__global__ __launch_bounds__(256) void k_adj(const float* __restrict__ G,
                                             const float* f1W, const float* f1b,
                                             const float* f2W, const float* f2b,
                                             const float* f3W, const float* f3b,
                                             float* __restrict__ adjw, void* __restrict__ outp,
                                             const float* __restrict__ flag) {
  __shared__ float Wc[32][64], Gl[32][64], bsum[32];
  int tid = threadIdx.x, tx = tid & 15, ty = tid >> 4;
  int v0 = blockIdx.y * 32, w0 = blockIdx.x * 32;
  float isf32 = flag[0];
  for (int e = tid; e < 2048; e += 256) {
    int w = e >> 6, c = e & 63;
    if (c < 60) {
      const float* src = c < 20 ? f1W : (c < 40 ? f2W : f3W);
      int dd = c < 20 ? c : (c < 40 ? c - 20 : c - 40);
      Wc[w][c] = src[(w0 + w) * 20 + dd];
    }
  }
  if (tid < 32) bsum[tid] = f1b[w0 + tid] + f2b[w0 + tid] + f3b[w0 + tid];
  float acc[2][2] = {};
  for (int bb = 0; bb < 32; ++bb) {
    __syncthreads();
    for (int e = tid; e < 2048; e += 256) {
      int r = e >> 6, c = e & 63;
      if (c < 60) Gl[r][c] = G[((size_t)bb * 512 + v0 + r) * 64 + c];
    }
    __syncthreads();
    const float4* g0 = (const float4*)Gl[ty * 2 + 0];
    const float4* g1 = (const float4*)Gl[ty * 2 + 1];
    const float4* w0p = (const float4*)Wc[tx * 2 + 0];
    const float4* w1p = (const float4*)Wc[tx * 2 + 1];
    float p00 = 0, p01 = 0, p10 = 0, p11 = 0;
#pragma unroll
    for (int q = 0; q < 15; ++q) {
      float4 a0 = g0[q], a1 = g1[q], b0 = w0p[q], b1 = w1p[q];
      p00 += a0.x * b0.x + a0.y * b0.y + a0.z * b0.z + a0.w * b0.w;
      p01 += a0.x * b1.x + a0.y * b1.y + a0.z * b1.z + a0.w * b1.w;
      p10 += a1.x * b0.x + a1.y * b0.y + a1.z * b0.z + a1.w * b0.w;
      p11 += a1.x * b1.x + a1.y * b1.y + a1.z * b1.z + a1.w * b1.w;
    }
    acc[0][0] += sigm((p00 + bsum[tx * 2 + 0]) * (1.f / 3.f));
    acc[0][1] += sigm((p01 + bsum[tx * 2 + 1]) * (1.f / 3.f));
    acc[1][0] += sigm((p10 + bsum[tx * 2 + 0]) * (1.f / 3.f));
    acc[1][1] += sigm((p11 + bsum[tx * 2 + 1]) * (1.f / 3.f));
  }
#pragma unroll
  for (int iv = 0; iv < 2; ++iv)
#pragma unroll
    for (int iw = 0; iw < 2; ++iw) {
      float a = sigm(acc[iv][iw] * (1.f / 32.f));
      size_t o = (size_t)(v0 + ty * 2 + iv) * 512 + (w0 + tx * 2 + iw);
      adjw[o] = a;
      if (isf32 > 0.5f) ((float*)outp)[196608 + o] = a;
      else ((bf16*)outp)[196608 + o] = __float2bfloat16(a);
    }
}

// ---------- start conv: X0[b][t][c][v], t=0 is the left zero-pad ----------
__global__ __launch_bounds__(256) void k_start(const float* __restrict__ in,
                                               const float* __restrict__ stW,
                                               const float* __restrict__ stb,
                                               float* __restrict__ X0) {
  __shared__ float w[32], bl[16];
  int tid = threadIdx.x;
  if (tid < 32) w[tid] = stW[tid];
  if (tid < 16) bl[tid] = stb[tid];
  __syncthreads();
  int blk = blockIdx.x;
  int b = blk / 26, rem = blk % 26, t = rem >> 1, v = (rem & 1) * 256 + tid;
  float f0 = 0.f, f1 = 0.f;
  if (t > 0) {
    size_t ib = (((size_t)(t - 1) * 32 + b) * 512 + v) * 2;
    f0 = in[ib];
    f1 = in[ib + 1];
  }
#pragma unroll
  for (int c = 0; c < 16; ++c)
    X0[((size_t)(b * 13 + t) * 16 + c) * 512 + v] = fmaf(w[c * 2], f0, fmaf(w[c * 2 + 1], f1, bl[c]));
}

// ---------- gated conv + skip(last t): U[b][t][c][v] ----------
__global__ __launch_bounds__(256) void k_gate(const float* __restrict__ X, float* __restrict__ U,
                                              float* __restrict__ skip,
                                              const float* fW, const float* fb,
                                              const float* gW, const float* gb,
                                              const float* sW, const float* sb,
                                              int i, int L, int Lo, int d) {
  __shared__ float wf[512], wg[512], swl[256], fbl[16], gbl[16], sbl[16];
  int tid = threadIdx.x;
  for (int e = tid; e < 512; e += 256) { wf[e] = fW[i * 512 + e]; wg[e] = gW[i * 512 + e]; }
  if (tid < 256) swl[tid] = sW[i * 256 + tid];
  if (tid < 16) { fbl[tid] = fb[i * 16 + tid]; gbl[tid] = gb[i * 16 + tid]; sbl[tid] = sb[i * 16 + tid]; }
  __syncthreads();
  int blk = blockIdx.x;
  int b = blk / (2 * Lo), rem = blk % (2 * Lo), t = rem >> 1, v = (rem & 1) * 256 + tid;
  float x0[16], x1[16];
  size_t base0 = (size_t)(b * L + t) * 16 * 512 + v;
  size_t base1 = (size_t)(b * L + t + d) * 16 * 512 + v;
#pragma unroll
  for (int ci = 0; ci < 16; ++ci) { x0[ci] = X[base0 + ci * 512]; x1[ci] = X[base1 + ci * 512]; }
  float u[16];
#pragma unroll
  for (int co = 0; co < 16; ++co) {
    float f = fbl[co], g = gbl[co];
#pragma unroll
    for (int ci = 0; ci < 16; ++ci) {
      f = fmaf(wf[co * 32 + ci * 2], x0[ci], f);
      f = fmaf(wf[co * 32 + ci * 2 + 1], x1[ci], f);
      g = fmaf(wg[co * 32 + ci * 2], x0[ci], g);
      g = fmaf(wg[co * 32 + ci * 2 + 1], x1[ci], g);
    }
    float uu = tanh_fast(f) * sigm(g);
    u[co] = uu;
    U[((size_t)(b * Lo + t) * 16 + co) * 512 + v] = uu;
  }
  if (t == Lo - 1) {
#pragma unroll
    for (int c = 0; c < 16; ++c) {
      float s = sbl[c];
#pragma unroll
      for (int ci = 0; ci < 16; ++ci) s = fmaf(swl[c * 16 + ci], u[ci], s);
      skip[((size_t)b * 16 + c) * 512 + v] += s;
    }
  }
}

// ---------- fp32 GEMM: C[M x Ncols] = A[M x 512] @ B; blockIdx.x<8 -> B0 else B1 ----------
__global__ __launch_bounds__(256) void k_gemm(const float* __restrict__ A,
                                              const float* __restrict__ B0,
                                              const float* __restrict__ B1,
                                              float* __restrict__ C, int ldc) {
  __shared__ float As[32][68];
  __shared__ float Bs[32][68];
  int bx = blockIdx.x, by = blockIdx.y;
  const float* __restrict__ Bp = (bx < 8) ? B0 : B1;
  int n0 = (bx & 7) * 64, m0 = by * 64;
  int tid = threadIdx.x, tx = tid & 15, ty = tid >> 4;
  float acc[4][4] = {};
  for (int kb = 0; kb < 512; kb += 32) {
#pragma unroll
    for (int s = 0; s < 2; ++s) {
      int f = tid + s * 256;
      int row = f >> 3, k4 = (f & 7) << 2;
      float4 a4 = *(const float4*)(A + (size_t)(m0 + row) * 512 + kb + k4);
      As[k4 + 0][row] = a4.x;
      As[k4 + 1][row] = a4.y;
      As[k4 + 2][row] = a4.z;
      As[k4 + 3][row] = a4.w;
      int kk = f >> 4, c4 = (f & 15) << 2;
      *(float4*)&Bs[kk][c4] = *(const float4*)(Bp + (size_t)(kb + kk) * 512 + n0 + c4);
    }
    __syncthreads();
#pragma unroll
    for (int kk = 0; kk < 32; ++kk) {
      float4 a = *(const float4*)&As[kk][ty << 2];
      float4 b = *(const float4*)&Bs[kk][tx << 2];
      float ar[4] = {a.x, a.y, a.z, a.w}, br[4] = {b.x, b.y, b.z, b.w};
#pragma unroll
      for (int r = 0; r < 4; ++r)
#pragma unroll
        for (int c = 0; c < 4; ++c) acc[r][c] = fmaf(ar[r], br[c], acc[r][c]);
    }
    __syncthreads();
  }
#pragma unroll
  for (int r = 0; r < 4; ++r) {
    float4 o = make_float4(acc[r][0], acc[r][1], acc[r][2], acc[r][3]);
    *(float4*)(C + (size_t)(m0 + (ty << 2) + r) * ldc + bx * 64 + (tx << 2)) = o;
  }
}

// ---------- combine: h = Wx*u + Wy1*y1 + Wy2*y2 + gb; x = BN(h + residual) ----------
__global__ __launch_bounds__(256) void k_combine(const float* __restrict__ U,
                                                 const float* __restrict__ Y,
                                                 const float* __restrict__ Xres,
                                                 float* __restrict__ Xn,
                                                 const float* __restrict__ ws,
                                                 const float* gcb, const float* bg, const float* bb,
                                                 const float* bm, const float* bv,
                                                 int i, int L, int Lo, int d) {
  __shared__ float wx[256], wy1[256], wy2[256], gbl[16], bsc[16], bsh[16];
  int tid = threadIdx.x;
  const float* we = ws + OFF_WEFF + (size_t)i * 768;
  if (tid < 256) { wx[tid] = we[tid]; wy1[tid] = we[256 + tid]; wy2[tid] = we[512 + tid]; }
  if (tid < 16) {
    gbl[tid] = gcb[i * 16 + tid];
    float sc = bg[i * 16 + tid] * rsqrtf(bv[i * 16 + tid] + 1e-5f);
    bsc[tid] = sc;
    bsh[tid] = bb[i * 16 + tid] - bm[i * 16 + tid] * sc;
  }
  __syncthreads();
  int blk = blockIdx.x;
  int b = blk / (2 * Lo), rem = blk % (2 * Lo), t = rem >> 1, v = (rem & 1) * 256 + tid;
  size_t rb = (size_t)(b * Lo + t) * 16;
  float uu[16], z1[16], z2[16];
#pragma unroll
  for (int ci = 0; ci < 16; ++ci) {
    uu[ci] = U[(rb + ci) * 512 + v];
    z1[ci] = Y[(rb + ci) * 1024 + v];
    z2[ci] = Y[(rb + ci) * 1024 + 512 + v];
  }
  size_t resb = (size_t)(b * L + t + d) * 16 * 512 + v;
#pragma unroll
  for (int co = 0; co < 16; ++co) {
    float h = gbl[co];
#pragma unroll
    for (int ci = 0; ci < 16; ++ci) {
      h = fmaf(wx[co * 16 + ci], uu[ci], h);
      h = fmaf(wy1[co * 16 + ci], z1[ci], h);
      h = fmaf(wy2[co * 16 + ci], z2[ci], h);
    }
    float val = h + Xres[resb + co * 512];
    val = fmaf(val, bsc[co], bsh[co]);
    Xn[(rb + co) * 512 + v] = val;
  }
}

// ---------- epilogue: relu(skip) -> end1 relu -> end2 -> out[b][h][v] ----------
__global__ __launch_bounds__(256) void k_end(const float* __restrict__ skip,
                                             const float* e1W, const float* e1b,
                                             const float* e2W, const float* e2b,
                                             void* __restrict__ outp,
                                             const float* __restrict__ flag) {
  __shared__ float w1[256], b1[16], w2[192], b2[12];
  int tid = threadIdx.x;
  if (tid < 256) w1[tid] = e1W[tid];
  if (tid < 192) w2[tid] = e2W[tid];
  if (tid < 16) b1[tid] = e1b[tid];
  if (tid < 12) b2[tid] = e2b[tid];
  __syncthreads();
  float isf32 = flag[0];
  int gid = blockIdx.x * 256 + tid;
  int b = gid >> 9, v = gid & 511;
  float sk[16], e1[16];
#pragma unroll
  for (int ci = 0; ci < 16; ++ci) sk[ci] = fmaxf(skip[((size_t)b * 16 + ci) * 512 + v], 0.f);
#pragma unroll
  for (int c = 0; c < 16; ++c) {
    float a = b1[c];
#pragma unroll
    for (int ci = 0; ci < 16; ++ci) a = fmaf(w1[c * 16 + ci], sk[ci], a);
    e1[c] = fmaxf(a, 0.f);
  }
#pragma unroll
  for (int h = 0; h < 12; ++h) {
    float o = b2[h];
#pragma unroll
    for (int ci = 0; ci < 16; ++ci) o = fmaf(w2[h * 16 + ci], e1[ci], o);
    size_t oi = ((size_t)b * 12 + h) * 512 + v;
    if (isf32 > 0.5f) ((float*)outp)[oi] = o;
    else ((bf16*)outp)[oi] = __float2bfloat16(o);
  }
}

extern "C" void kernel_launch(void* const* d_in, const int* in_sizes, int n_in,
                              void* d_out, int out_size, void* d_ws, size_t ws_size,
                              hipStream_t stream) {
  float* ws = (float*)d_ws;
  if (ws_size < WS_TOTAL * sizeof(float)) return;  // fail loudly (output stays wrong)

  // element counts per input, reference order
  static const int CSZ[27] = {393216, 32, 16, 4096, 128, 4096, 128, 2048, 128, 8192, 128,
                              128, 128, 128, 128, 256, 16, 192, 12, 480, 20,
                              10240, 512, 10240, 512, 10240, 512};
  float* cv[27];
  {
    size_t off = OFF_CIN;
    for (int i = 0; i < 27; ++i) { cv[i] = ws + off; off += (size_t)CSZ[i]; }
  }
  float* flag = ws + OFF_FLAG;

  k_detect<<<1, 256, 0, stream>>>(d_in[0], flag);
  for (int i = 0; i < 27; ++i)
    k_conv<<<(CSZ[i] + 255) / 256, 256, 0, stream>>>(d_in[i], cv[i], CSZ[i], flag);

  const float* IN = cv[0];
  const float* stW = cv[1];  const float* stb = cv[2];
  const float* fW = cv[3];   const float* fb = cv[4];
  const float* gW = cv[5];   const float* gb = cv[6];
  const float* sW = cv[7];   const float* sb = cv[8];
  const float* gcW = cv[9];  const float* gcb = cv[10];
  const float* bng = cv[11]; const float* bnb = cv[12];
  const float* bnm = cv[13]; const float* bnv = cv[14];
  const float* e1W = cv[15]; const float* e1b = cv[16];
  const float* e2W = cv[17]; const float* e2b = cv[18];
  const float* linW = cv[19]; const float* linb = cv[20];
  const float* f1W = cv[21]; const float* f1b = cv[22];
  const float* f2W = cv[23]; const float* f2b = cv[24];
  const float* f3W = cv[25]; const float* f3b = cv[26];

  hipMemsetAsync(ws + OFF_SKIP, 0, (size_t)B_ * CH_ * V_ * sizeof(float), stream);
  k_pre<<<12, 256, 0, stream>>>(linW, gcW, ws);
  k_fft<<<64, 256, 0, stream>>>(IN, linb, ws, ws + OFF_R, ws + OFF_I, ws + OFF_G);
  k_irfft<<<640, 256, 0, stream>>>(ws + OFF_R, ws + OFF_I, ws, ws + OFF_G);
  k_adj<<<dim3(16, 16), 256, 0, stream>>>(ws + OFF_G, f1W, f1b, f2W, f2b, f3W, f3b,
                                          ws + OFF_ADJ, d_out, flag);
  k_gemm<<<dim3(8, 8), 256, 0, stream>>>(ws + OFF_ADJ, ws + OFF_ADJ, ws + OFF_ADJ,
                                         ws + OFF_ADJ2, 512);
  k_start<<<832, 256, 0, stream>>>(IN, stW, stb, ws + OFF_X0);

  float* cur = ws + OFF_X0;
  float* nxt = ws + OFF_X1;
  int L = 13;
  const int dils[8] = {1, 2, 1, 2, 1, 2, 1, 2};
  for (int i = 0; i < 8; ++i) {
    int d = dils[i], Lo = L - d;
    k_gate<<<64 * Lo, 256, 0, stream>>>(cur, ws + OFF_U, ws + OFF_SKIP,
                                        fW, fb, gW, gb, sW, sb, i, L, Lo, d);
    k_gemm<<<dim3(16, 8 * Lo), 256, 0, stream>>>(ws + OFF_U, ws + OFF_ADJ, ws + OFF_ADJ2,
                                                 ws + OFF_Y, 1024);
    k_combine<<<64 * Lo, 256, 0, stream>>>(ws + OFF_U, ws + OFF_Y, cur, nxt, ws,
                                           gcb, bng, bnb, bnm, bnv, i, L, Lo, d);
    float* tmp = cur; cur = nxt; nxt = tmp;
    L = Lo;
  }
  k_end<<<64, 256, 0, stream>>>(ws + OFF_SKIP, e1W, e1b, e2W, e2b, d_out, flag);
}

// Round 3
// 703.769 us; speedup vs baseline: 1.4446x; 1.4446x over previous
//
#include <hip/hip_runtime.h>
#include <hip/hip_bf16.h>

using bf16 = __hip_bfloat16;
typedef unsigned short ushort_t;
typedef float f32x4 __attribute__((ext_vector_type(4)));
typedef short bf16x8 __attribute__((ext_vector_type(8)));

__device__ __forceinline__ float tof(bf16 x) { return __bfloat162float(x); }
__device__ __forceinline__ float tofu(ushort_t u) { return __uint_as_float((unsigned)u << 16); }
__device__ __forceinline__ ushort_t f2bf(float x) {
  unsigned u = __float_as_uint(x);
  return (ushort_t)((u + 0x7FFF + ((u >> 16) & 1)) >> 16);  // RNE
}
__device__ __forceinline__ float sigm(float x) { return 1.f / (1.f + __expf(-x)); }
__device__ __forceinline__ float tanh_fast(float x) {
  float e2 = __expf(2.f * x);
  return 1.f - 2.f / (e2 + 1.f);
}

#define B_ 32
#define V_ 512
#define EPS_ 0.3f

// ---- workspace layout (float elements) ----
constexpr size_t OFF_TWC  = 0;          // 512
constexpr size_t OFF_TWS  = 512;        // 512
constexpr size_t OFF_C    = 1024;       // 480
constexpr size_t OFF_S    = 1504;       // 480
constexpr size_t OFF_WEFF = 1984;       // 6144 [8][3][16][16]
constexpr size_t OFF_R    = 8128;       // [32][512][20]  (dead after irfft)
constexpr size_t OFF_I    = 335808;     // [32][512][20]  (dead after irfft)
constexpr size_t OFF_PADJ = 8128;       // [512][512] partial sums (reuses R)
constexpr size_t OFF_WCT  = 270272;     // WcT[64][512] + bsum[512] (reuses R tail)
constexpr size_t OFF_G    = 663488;     // [32][512][64] (dead after k_adj)
constexpr size_t OFF_BTHI = 663488;     // bf16 BT_hi [1024][512] (reuses G)
constexpr size_t OFF_BTLO = 925632;     // bf16 BT_lo [1024][512]
constexpr size_t OFF_ADJ  = 1712064;    // [512][512]
constexpr size_t OFF_ADJ2 = 1974208;    // [512][512]
constexpr size_t OFF_SKIP = 2236352;    // [32][16][512]
constexpr size_t OFF_X0   = 2498496;    // [32][13][16][512]
constexpr size_t OFF_X1   = 5906368;
constexpr size_t OFF_UHI  = 9314240;    // bf16 [6144][512]
constexpr size_t OFF_ULO  = 10887104;   // bf16 [6144][512]
constexpr size_t OFF_Y    = 12722112;   // [6144][1024]
constexpr size_t OFF_FLAG = 19013568;   // 8
constexpr size_t OFF_CIN  = 19013576;   // converted fp32 inputs (445952)
constexpr size_t WS_TOTAL = 19459584;   // same footprint as round 2 (passed)

// ---------- dtype detection ----------
__global__ __launch_bounds__(256) void k_detect(const void* __restrict__ in0,
                                                float* __restrict__ flag) {
  __shared__ int cnt;
  if (threadIdx.x == 0) cnt = 0;
  __syncthreads();
  const unsigned short* u = (const unsigned short*)in0;
  int bad = 0;
  for (int i = threadIdx.x; i < 4096; i += 256) {
    int e = (u[i] >> 7) & 0xFF;
    if (e == 255 || (e != 0 && (e < 87 || e > 167))) bad++;
  }
  atomicAdd(&cnt, bad);
  __syncthreads();
  if (threadIdx.x == 0) flag[0] = (cnt > 200) ? 1.f : 0.f;
}

// ---------- input conversion (vectorized x4) ----------
__global__ __launch_bounds__(256) void k_convin(const void* __restrict__ src,
                                                float* __restrict__ dst,
                                                const float* __restrict__ flag) {
  int i4 = blockIdx.x * 256 + threadIdx.x;  // 98304 total
  if (flag[0] > 0.5f) {
    ((float4*)dst)[i4] = ((const float4*)src)[i4];
  } else {
    ushort4 v = ((const ushort4*)src)[i4];
    dst[i4 * 4 + 0] = tofu(v.x);
    dst[i4 * 4 + 1] = tofu(v.y);
    dst[i4 * 4 + 2] = tofu(v.z);
    dst[i4 * 4 + 3] = tofu(v.w);
  }
}

// ---------- all 26 weight arrays in one kernel ----------
struct P26 { const void* p[26]; };
__global__ __launch_bounds__(256) void k_convw(P26 ps, float* __restrict__ dst,
                                               const float* __restrict__ flag) {
  const int sz[26] = {32, 16, 4096, 128, 4096, 128, 2048, 128, 8192, 128,
                      128, 128, 128, 128, 256, 16, 192, 12, 480, 20,
                      10240, 512, 10240, 512, 10240, 512};
  int gid = blockIdx.x * 256 + threadIdx.x;
  if (gid >= 52736) return;
  int s = 0, off = 0;
  while (gid >= off + sz[s]) { off += sz[s]; ++s; }
  int local = gid - off;
  float v = (flag[0] > 0.5f) ? ((const float*)ps.p[s])[local]
                             : tofu(((const ushort_t*)ps.p[s])[local]);
  dst[gid] = v;
}

// ---------- precompute: twiddles, folded-FFT matrices, effective gconv weights ----------
__global__ __launch_bounds__(256) void k_pre(const float* __restrict__ linW,
                                             const float* __restrict__ gconvW,
                                             float* __restrict__ ws) {
  int idx = blockIdx.x * 256 + threadIdx.x;
  const float TWO_PI = 6.2831853071795864769f;
  if (idx < 512) {
    float ang = TWO_PI * (float)idx / 512.f;
    ws[OFF_TWC + idx] = cosf(ang);
    ws[OFF_TWS + idx] = sinf(ang);
  } else if (idx < 992) {
    int e = idx - 512, d = e / 24, n = e % 24;
    float c = 0.f, s = 0.f;
    for (int k = 0; k < 24; ++k) {
      int j = (k * n) % 24;
      float ang = TWO_PI * (float)j / 24.f;
      float w = linW[d * 24 + k];
      c += w * cosf(ang);
      s -= w * sinf(ang);
    }
    ws[OFF_C + e] = c;
    ws[OFF_S + e] = s;
  } else if (idx < 992 + 2048) {
    int e = idx - 992, i = e >> 8, co = (e >> 4) & 15, ci = e & 15;
    size_t base = (size_t)(i * 16 + co) * 64 + ci;
    float W0 = gconvW[base];
    float W1 = gconvW[base + 16];
    float W2 = gconvW[base + 32];
    float W3 = gconvW[base + 48];
    size_t o = OFF_WEFF + (size_t)i * 768 + co * 16 + ci;
    ws[o]       = EPS_ * (W0 + W2) + EPS_ * EPS_ * (W1 + W3);
    ws[o + 256] = (W0 - W2) + 2.f * EPS_ * (W1 - W3);
    ws[o + 512] = W1 + W3;
  }
}

// ---------- FFT(24) folded into lin_W ----------
__global__ __launch_bounds__(256) void k_fft(const float* __restrict__ in,
                                             const float* __restrict__ linb,
                                             const float* __restrict__ ws,
                                             float* __restrict__ Rw, float* __restrict__ Iw,
                                             float* __restrict__ G) {
  __shared__ float Cl[480], Sl[480], lb[20];
  int tid = threadIdx.x;
  for (int e = tid; e < 480; e += 256) { Cl[e] = ws[OFF_C + e]; Sl[e] = ws[OFF_S + e]; }
  if (tid < 20) lb[tid] = linb[tid];
  __syncthreads();
  int gid = blockIdx.x * 256 + tid;
  int b = gid >> 9, v = gid & 511;
  float xr[24];
#pragma unroll
  for (int t = 0; t < 12; ++t) {
    size_t ib = (((size_t)t * 32 + b) * 512 + v) * 2;
    xr[2 * t] = in[ib];
    xr[2 * t + 1] = in[ib + 1];
  }
  size_t gbv = (size_t)b * 512 + v;
  for (int d = 0; d < 20; ++d) {
    float R = lb[d], I = lb[d];
#pragma unroll
    for (int n = 0; n < 24; ++n) {
      R = fmaf(xr[n], Cl[d * 24 + n], R);
      I = fmaf(xr[n], Sl[d * 24 + n], I);
    }
    Rw[gbv * 20 + d] = R;
    Iw[gbv * 20 + d] = I;
    G[gbv * 64 + 20 + d] = sqrtf(R * R + I * I);
    G[gbv * 64 + 40 + d] = atanf(R / (I + 1e-4f));
  }
  G[gbv * 64 + 60] = 0.f; G[gbv * 64 + 61] = 0.f;
  G[gbv * 64 + 62] = 0.f; G[gbv * 64 + 63] = 0.f;
}

// ---------- irfft(n=512) along v ----------
__global__ __launch_bounds__(256) void k_irfft(const float* __restrict__ Rw,
                                               const float* __restrict__ Iw,
                                               const float* __restrict__ ws,
                                               float* __restrict__ G) {
  __shared__ float Rk[257], Ik[257], twc[512], tws[512];
  int blk = blockIdx.x;
  int b = blk / 20, d = blk % 20;
  int tid = threadIdx.x;
  for (int e = tid; e < 512; e += 256) { twc[e] = ws[OFF_TWC + e]; tws[e] = ws[OFF_TWS + e]; }
  for (int k = tid; k < 257; k += 256) {
    float ck = (k == 0 || k == 256) ? 1.f : 2.f;
    Rk[k] = Rw[((size_t)b * 512 + k) * 20 + d] * ck;
    Ik[k] = Iw[((size_t)b * 512 + k) * 20 + d] * ck;
  }
  __syncthreads();
#pragma unroll
  for (int s = 0; s < 2; ++s) {
    int m = tid + s * 256;
    float acc = 0.f;
    for (int k = 0; k < 257; ++k) {
      int j = (k * m) & 511;
      acc += Rk[k] * twc[j] - Ik[k] * tws[j];
    }
    G[((size_t)b * 512 + m) * 64 + d] = acc * (1.f / 512.f);
  }
}

// ---------- WcT[64][512] + bsum[512] ----------
__global__ __launch_bounds__(256) void k_wct(const float* f1W, const float* f1b,
                                             const float* f2W, const float* f2b,
                                             const float* f3W, const float* f3b,
                                             float* __restrict__ wct) {
  int idx = blockIdx.x * 256 + threadIdx.x;
  if (idx < 32768) {
    int k = idx >> 9, w = idx & 511;
    float v = 0.f;
    if (k < 20) v = f1W[w * 20 + k];
    else if (k < 40) v = f2W[w * 20 + k - 20];
    else if (k < 60) v = f3W[w * 20 + k - 40];
    wct[idx] = v;
  } else if (idx < 33280) {
    int w = idx - 32768;
    wct[idx] = f1b[w] + f2b[w] + f3b[w];
  }
}

// ---------- adj partial: 64x64 tile, K=64, 2 batches per block, grid (8,8,16) ----------
__global__ __launch_bounds__(256) void k_adj(const float* __restrict__ G,
                                             const float* __restrict__ wct,
                                             float* __restrict__ padj) {
  __shared__ float As[64 * 68], Bs[64 * 68], bsl[64];
  int tid = threadIdx.x, tx = tid & 15, ty = tid >> 4;
  int w0 = blockIdx.x * 64, m0 = blockIdx.y * 64, z = blockIdx.z;
  for (int i = 0; i < 16; ++i) {
    int idx = tid + i * 256;
    Bs[(idx >> 6) * 68 + (idx & 63)] = wct[(size_t)(idx >> 6) * 512 + w0 + (idx & 63)];
  }
  if (tid < 64) bsl[tid] = wct[32768 + w0 + tid];
  float sum[4][4] = {};
  for (int bi = 0; bi < 2; ++bi) {
    int bb = z * 2 + bi;
    __syncthreads();
    for (int i = 0; i < 4; ++i) {
      int idx = tid + i * 256;
      int row = idx >> 4, seg = idx & 15;
      float4 g = *(const float4*)&G[((size_t)bb * 512 + m0 + row) * 64 + seg * 4];
      As[(seg * 4 + 0) * 68 + row] = g.x;
      As[(seg * 4 + 1) * 68 + row] = g.y;
      As[(seg * 4 + 2) * 68 + row] = g.z;
      As[(seg * 4 + 3) * 68 + row] = g.w;
    }
    __syncthreads();
    float dot[4][4] = {};
    for (int kk = 0; kk < 64; ++kk) {
      float4 a = *(const float4*)&As[kk * 68 + ty * 4];
      float4 b = *(const float4*)&Bs[kk * 68 + tx * 4];
      float ar[4] = {a.x, a.y, a.z, a.w}, br[4] = {b.x, b.y, b.z, b.w};
#pragma unroll
      for (int r = 0; r < 4; ++r)
#pragma unroll
        for (int c = 0; c < 4; ++c) dot[r][c] = fmaf(ar[r], br[c], dot[r][c]);
    }
#pragma unroll
    for (int r = 0; r < 4; ++r)
#pragma unroll
      for (int c = 0; c < 4; ++c)
        sum[r][c] += sigm((dot[r][c] + bsl[tx * 4 + c]) * (1.f / 3.f));
  }
#pragma unroll
  for (int r = 0; r < 4; ++r)
#pragma unroll
    for (int c = 0; c < 4; ++c)
      atomicAdd(&padj[(size_t)(m0 + ty * 4 + r) * 512 + w0 + tx * 4 + c], sum[r][c]);
}

// ---------- finalize adj ----------
__global__ __launch_bounds__(256) void k_adjfin(const float* __restrict__ padj,
                                                float* __restrict__ adjw,
                                                void* __restrict__ outp,
                                                const float* __restrict__ flag) {
  int idx = blockIdx.x * 256 + threadIdx.x;  // grid 1024
  float a = sigm(padj[idx] * (1.f / 32.f));
  adjw[idx] = a;
  if (flag[0] > 0.5f) ((float*)outp)[196608 + idx] = a;
  else ((ushort_t*)outp)[196608 + idx] = f2bf(a);
}

// ---------- fp32 GEMM (adj2 = adj @ adj only) ----------
__global__ __launch_bounds__(256) void k_gemm(const float* __restrict__ A,
                                              const float* __restrict__ B0,
                                              const float* __restrict__ B1,
                                              float* __restrict__ C, int ldc) {
  __shared__ float As[32][68];
  __shared__ float Bs[32][68];
  int bx = blockIdx.x, by = blockIdx.y;
  const float* __restrict__ Bp = (bx < 8) ? B0 : B1;
  int n0 = (bx & 7) * 64, m0 = by * 64;
  int tid = threadIdx.x, tx = tid & 15, ty = tid >> 4;
  float acc[4][4] = {};
  for (int kb = 0; kb < 512; kb += 32) {
#pragma unroll
    for (int s = 0; s < 2; ++s) {
      int f = tid + s * 256;
      int row = f >> 3, k4 = (f & 7) << 2;
      float4 a4 = *(const float4*)(A + (size_t)(m0 + row) * 512 + kb + k4);
      As[k4 + 0][row] = a4.x;
      As[k4 + 1][row] = a4.y;
      As[k4 + 2][row] = a4.z;
      As[k4 + 3][row] = a4.w;
      int kk = f >> 4, c4 = (f & 15) << 2;
      *(float4*)&Bs[kk][c4] = *(const float4*)(Bp + (size_t)(kb + kk) * 512 + n0 + c4);
    }
    __syncthreads();
#pragma unroll
    for (int kk = 0; kk < 32; ++kk) {
      float4 a = *(const float4*)&As[kk][ty << 2];
      float4 b = *(const float4*)&Bs[kk][tx << 2];
      float ar[4] = {a.x, a.y, a.z, a.w}, br[4] = {b.x, b.y, b.z, b.w};
#pragma unroll
      for (int r = 0; r < 4; ++r)
#pragma unroll
        for (int c = 0; c < 4; ++c) acc[r][c] = fmaf(ar[r], br[c], acc[r][c]);
    }
    __syncthreads();
  }
#pragma unroll
  for (int r = 0; r < 4; ++r) {
    float4 o = make_float4(acc[r][0], acc[r][1], acc[r][2], acc[r][3]);
    *(float4*)(C + (size_t)(m0 + (ty << 2) + r) * ldc + bx * 64 + (tx << 2)) = o;
  }
}

// ---------- split B = [adjT | adj2T] into bf16 hi/lo, transposed to [n][k] ----------
__global__ __launch_bounds__(256) void k_splitB(const float* __restrict__ adjw,
                                                const float* __restrict__ adj2w,
                                                ushort_t* __restrict__ Bh,
                                                ushort_t* __restrict__ Bl) {
  __shared__ float til[32][33];
  int tid = threadIdx.x;
  int k0 = blockIdx.x * 32;
  int nb = blockIdx.y;  // 0..31
  const float* src = (nb < 16) ? adjw : adj2w;
  int ns = (nb * 32) & 511;
  for (int i = 0; i < 4; ++i) {
    int idx = tid + i * 256;
    int r = idx >> 5, c = idx & 31;
    til[r][c] = src[(size_t)(k0 + r) * 512 + ns + c];
  }
  __syncthreads();
  for (int i = 0; i < 4; ++i) {
    int idx = tid + i * 256;
    int rr = idx >> 5, cc = idx & 31;
    float v = til[cc][rr];
    ushort_t h = f2bf(v);
    float hf = tofu(h);
    ushort_t l = f2bf(v - hf);
    size_t o = (size_t)(nb * 32 + rr) * 512 + k0 + cc;
    Bh[o] = h;
    Bl[o] = l;
  }
}

// ---------- start conv ----------
__global__ __launch_bounds__(256) void k_start(const float* __restrict__ in,
                                               const float* __restrict__ stW,
                                               const float* __restrict__ stb,
                                               float* __restrict__ X0) {
  __shared__ float w[32], bl[16];
  int tid = threadIdx.x;
  if (tid < 32) w[tid] = stW[tid];
  if (tid < 16) bl[tid] = stb[tid];
  __syncthreads();
  int blk = blockIdx.x;
  int b = blk / 26, rem = blk % 26, t = rem >> 1, v = (rem & 1) * 256 + tid;
  float f0 = 0.f, f1 = 0.f;
  if (t > 0) {
    size_t ib = (((size_t)(t - 1) * 32 + b) * 512 + v) * 2;
    f0 = in[ib];
    f1 = in[ib + 1];
  }
#pragma unroll
  for (int c = 0; c < 16; ++c)
    X0[((size_t)(b * 13 + t) * 16 + c) * 512 + v] = fmaf(w[c * 2], f0, fmaf(w[c * 2 + 1], f1, bl[c]));
}

// ---------- gated conv + skip + bf16 hi/lo split of U ----------
__global__ __launch_bounds__(256) void k_gate(const float* __restrict__ X,
                                              ushort_t* __restrict__ Uhi,
                                              ushort_t* __restrict__ Ulo,
                                              float* __restrict__ skip,
                                              const float* fW, const float* fb,
                                              const float* gW, const float* gb,
                                              const float* sW, const float* sb,
                                              int i, int L, int Lo, int d) {
  __shared__ float wf[512], wg[512], swl[256], fbl[16], gbl[16], sbl[16];
  int tid = threadIdx.x;
  for (int e = tid; e < 512; e += 256) { wf[e] = fW[i * 512 + e]; wg[e] = gW[i * 512 + e]; }
  if (tid < 256) swl[tid] = sW[i * 256 + tid];
  if (tid < 16) { fbl[tid] = fb[i * 16 + tid]; gbl[tid] = gb[i * 16 + tid]; sbl[tid] = sb[i * 16 + tid]; }
  __syncthreads();
  int blk = blockIdx.x;
  int b = blk / (2 * Lo), rem = blk % (2 * Lo), t = rem >> 1, v = (rem & 1) * 256 + tid;
  float x0[16], x1[16];
  size_t base0 = (size_t)(b * L + t) * 16 * 512 + v;
  size_t base1 = (size_t)(b * L + t + d) * 16 * 512 + v;
#pragma unroll
  for (int ci = 0; ci < 16; ++ci) { x0[ci] = X[base0 + ci * 512]; x1[ci] = X[base1 + ci * 512]; }
  float u[16];
#pragma unroll
  for (int co = 0; co < 16; ++co) {
    float f = fbl[co], g = gbl[co];
#pragma unroll
    for (int ci = 0; ci < 16; ++ci) {
      f = fmaf(wf[co * 32 + ci * 2], x0[ci], f);
      f = fmaf(wf[co * 32 + ci * 2 + 1], x1[ci], f);
      g = fmaf(wg[co * 32 + ci * 2], x0[ci], g);
      g = fmaf(wg[co * 32 + ci * 2 + 1], x1[ci], g);
    }
    float uu = tanh_fast(f) * sigm(g);
    u[co] = uu;
    ushort_t h = f2bf(uu);
    float hf = tofu(h);
    ushort_t l = f2bf(uu - hf);
    size_t o = ((size_t)(b * Lo + t) * 16 + co) * 512 + v;
    Uhi[o] = h;
    Ulo[o] = l;
  }
  if (t == Lo - 1) {
#pragma unroll
    for (int c = 0; c < 16; ++c) {
      float s = sbl[c];
#pragma unroll
      for (int ci = 0; ci < 16; ++ci) s = fmaf(swl[c * 16 + ci], u[ci], s);
      skip[((size_t)b * 16 + c) * 512 + v] += s;
    }
  }
}

// ---------- bf16 MFMA GEMM, 3-term hi/lo split: Y[M x 1024] = U @ [adj|adj2] ----------
__global__ __launch_bounds__(256) void k_mfma(const ushort_t* __restrict__ Ah_g,
                                              const ushort_t* __restrict__ Al_g,
                                              const ushort_t* __restrict__ Bh_g,
                                              const ushort_t* __restrict__ Bl_g,
                                              float* __restrict__ Y) {
  __shared__ ushort_t Ah[128 * 40], Al[128 * 40], Bh[128 * 40], Bl[128 * 40];
  int tid = threadIdx.x;
  int lane = tid & 63, wv = tid >> 6;
  int quad = lane >> 4, l15 = lane & 15;
  int wr = wv >> 1, wc = wv & 1;
  int n0 = blockIdx.x * 128, m0 = blockIdx.y * 128;
  f32x4 acc[4][4] = {};
  for (int kt = 0; kt < 16; ++kt) {
    int k0 = kt * 32;
#pragma unroll
    for (int r = 0; r < 2; ++r) {
      int u = tid + r * 256;  // 0..511
      int row = u >> 2, seg = u & 3;
      size_t goA = ((size_t)(m0 + row)) * 512 + k0 + seg * 8;
      size_t goB = ((size_t)(n0 + row)) * 512 + k0 + seg * 8;
      int lo = row * 40 + seg * 8;
      *(uint4*)&Ah[lo] = *(const uint4*)&Ah_g[goA];
      *(uint4*)&Al[lo] = *(const uint4*)&Al_g[goA];
      *(uint4*)&Bh[lo] = *(const uint4*)&Bh_g[goB];
      *(uint4*)&Bl[lo] = *(const uint4*)&Bl_g[goB];
    }
    __syncthreads();
    bf16x8 afh[4], afl[4], bfh[4], bfl[4];
#pragma unroll
    for (int i = 0; i < 4; ++i) {
      int mr = (wr * 64 + i * 16 + l15) * 40 + quad * 8;
      afh[i] = *(const bf16x8*)&Ah[mr];
      afl[i] = *(const bf16x8*)&Al[mr];
      int nr = (wc * 64 + i * 16 + l15) * 40 + quad * 8;
      bfh[i] = *(const bf16x8*)&Bh[nr];
      bfl[i] = *(const bf16x8*)&Bl[nr];
    }
#pragma unroll
    for (int i = 0; i < 4; ++i)
#pragma unroll
      for (int j = 0; j < 4; ++j) {
        acc[i][j] = __builtin_amdgcn_mfma_f32_16x16x32_bf16(afh[i], bfh[j], acc[i][j], 0, 0, 0);
        acc[i][j] = __builtin_amdgcn_mfma_f32_16x16x32_bf16(afh[i], bfl[j], acc[i][j], 0, 0, 0);
        acc[i][j] = __builtin_amdgcn_mfma_f32_16x16x32_bf16(afl[i], bfh[j], acc[i][j], 0, 0, 0);
      }
    __syncthreads();
  }
#pragma unroll
  for (int i = 0; i < 4; ++i)
#pragma unroll
    for (int j = 0; j < 4; ++j)
#pragma unroll
      for (int r = 0; r < 4; ++r) {
        int row = m0 + wr * 64 + i * 16 + quad * 4 + r;
        int col = n0 + wc * 64 + j * 16 + l15;
        Y[(size_t)row * 1024 + col] = acc[i][j][r];
      }
}

// ---------- combine: h = Wx*u + Wy1*y1 + Wy2*y2 + gb; x = BN(h + residual) ----------
__global__ __launch_bounds__(256) void k_combine(const ushort_t* __restrict__ Uhi,
                                                 const ushort_t* __restrict__ Ulo,
                                                 const float* __restrict__ Y,
                                                 const float* __restrict__ Xres,
                                                 float* __restrict__ Xn,
                                                 const float* __restrict__ ws,
                                                 const float* gcb, const float* bg, const float* bb,
                                                 const float* bm, const float* bv,
                                                 int i, int L, int Lo, int d) {
  __shared__ float wx[256], wy1[256], wy2[256], gbl[16], bsc[16], bsh[16];
  int tid = threadIdx.x;
  const float* we = ws + OFF_WEFF + (size_t)i * 768;
  if (tid < 256) { wx[tid] = we[tid]; wy1[tid] = we[256 + tid]; wy2[tid] = we[512 + tid]; }
  if (tid < 16) {
    gbl[tid] = gcb[i * 16 + tid];
    float sc = bg[i * 16 + tid] * rsqrtf(bv[i * 16 + tid] + 1e-5f);
    bsc[tid] = sc;
    bsh[tid] = bb[i * 16 + tid] - bm[i * 16 + tid] * sc;
  }
  __syncthreads();
  int blk = blockIdx.x;
  int b = blk / (2 * Lo), rem = blk % (2 * Lo), t = rem >> 1, v = (rem & 1) * 256 + tid;
  size_t rb = (size_t)(b * Lo + t) * 16;
  float uu[16], z1[16], z2[16];
#pragma unroll
  for (int ci = 0; ci < 16; ++ci) {
    size_t o = (rb + ci) * 512 + v;
    uu[ci] = tofu(Uhi[o]) + tofu(Ulo[o]);
    z1[ci] = Y[(rb + ci) * 1024 + v];
    z2[ci] = Y[(rb + ci) * 1024 + 512 + v];
  }
  size_t resb = (size_t)(b * L + t + d) * 16 * 512 + v;
#pragma unroll
  for (int co = 0; co < 16; ++co) {
    float h = gbl[co];
#pragma unroll
    for (int ci = 0; ci < 16; ++ci) {
      h = fmaf(wx[co * 16 + ci], uu[ci], h);
      h = fmaf(wy1[co * 16 + ci], z1[ci], h);
      h = fmaf(wy2[co * 16 + ci], z2[ci], h);
    }
    float val = h + Xres[resb + co * 512];
    val = fmaf(val, bsc[co], bsh[co]);
    Xn[(rb + co) * 512 + v] = val;
  }
}

// ---------- epilogue ----------
__global__ __launch_bounds__(256) void k_end(const float* __restrict__ skip,
                                             const float* e1W, const float* e1b,
                                             const float* e2W, const float* e2b,
                                             void* __restrict__ outp,
                                             const float* __restrict__ flag) {
  __shared__ float w1[256], b1[16], w2[192], b2[12];
  int tid = threadIdx.x;
  if (tid < 256) w1[tid] = e1W[tid];
  if (tid < 192) w2[tid] = e2W[tid];
  if (tid < 16) b1[tid] = e1b[tid];
  if (tid < 12) b2[tid] = e2b[tid];
  __syncthreads();
  float isf32 = flag[0];
  int gid = blockIdx.x * 256 + tid;
  int b = gid >> 9, v = gid & 511;
  float sk[16], e1[16];
#pragma unroll
  for (int ci = 0; ci < 16; ++ci) sk[ci] = fmaxf(skip[((size_t)b * 16 + ci) * 512 + v], 0.f);
#pragma unroll
  for (int c = 0; c < 16; ++c) {
    float a = b1[c];
#pragma unroll
    for (int ci = 0; ci < 16; ++ci) a = fmaf(w1[c * 16 + ci], sk[ci], a);
    e1[c] = fmaxf(a, 0.f);
  }
#pragma unroll
  for (int h = 0; h < 12; ++h) {
    float o = b2[h];
#pragma unroll
    for (int ci = 0; ci < 16; ++ci) o = fmaf(w2[h * 16 + ci], e1[ci], o);
    size_t oi = ((size_t)b * 12 + h) * 512 + v;
    if (isf32 > 0.5f) ((float*)outp)[oi] = o;
    else ((ushort_t*)outp)[oi] = f2bf(o);
  }
}

extern "C" void kernel_launch(void* const* d_in, const int* in_sizes, int n_in,
                              void* d_out, int out_size, void* d_ws, size_t ws_size,
                              hipStream_t stream) {
  float* ws = (float*)d_ws;
  if (ws_size < WS_TOTAL * sizeof(float)) return;

  static const int CSZ[27] = {393216, 32, 16, 4096, 128, 4096, 128, 2048, 128, 8192, 128,
                              128, 128, 128, 128, 256, 16, 192, 12, 480, 20,
                              10240, 512, 10240, 512, 10240, 512};
  float* cv[27];
  {
    size_t off = OFF_CIN;
    for (int i = 0; i < 27; ++i) { cv[i] = ws + off; off += (size_t)CSZ[i]; }
  }
  float* flag = ws + OFF_FLAG;

  k_detect<<<1, 256, 0, stream>>>(d_in[0], flag);
  k_convin<<<384, 256, 0, stream>>>(d_in[0], cv[0], flag);
  P26 ps;
  for (int i = 0; i < 26; ++i) ps.p[i] = d_in[i + 1];
  k_convw<<<206, 256, 0, stream>>>(ps, cv[1], flag);

  const float* IN = cv[0];
  const float* stW = cv[1];  const float* stb = cv[2];
  const float* fW = cv[3];   const float* fb = cv[4];
  const float* gW = cv[5];   const float* gb = cv[6];
  const float* sW = cv[7];   const float* sb = cv[8];
  const float* gcW = cv[9];  const float* gcb = cv[10];
  const float* bng = cv[11]; const float* bnb = cv[12];
  const float* bnm = cv[13]; const float* bnv = cv[14];
  const float* e1W = cv[15]; const float* e1b = cv[16];
  const float* e2W = cv[17]; const float* e2b = cv[18];
  const float* linW = cv[19]; const float* linb = cv[20];
  const float* f1W = cv[21]; const float* f1b = cv[22];
  const float* f2W = cv[23]; const float* f2b = cv[24];
  const float* f3W = cv[25]; const float* f3b = cv[26];

  hipMemsetAsync(ws + OFF_SKIP, 0, (size_t)B_ * 16 * V_ * sizeof(float), stream);
  k_pre<<<12, 256, 0, stream>>>(linW, gcW, ws);
  k_fft<<<64, 256, 0, stream>>>(IN, linb, ws, ws + OFF_R, ws + OFF_I, ws + OFF_G);
  k_irfft<<<640, 256, 0, stream>>>(ws + OFF_R, ws + OFF_I, ws, ws + OFF_G);
  k_wct<<<130, 256, 0, stream>>>(f1W, f1b, f2W, f2b, f3W, f3b, ws + OFF_WCT);
  hipMemsetAsync(ws + OFF_PADJ, 0, 262144 * sizeof(float), stream);
  k_adj<<<dim3(8, 8, 16), 256, 0, stream>>>(ws + OFF_G, ws + OFF_WCT, ws + OFF_PADJ);
  k_adjfin<<<1024, 256, 0, stream>>>(ws + OFF_PADJ, ws + OFF_ADJ, d_out, flag);
  k_gemm<<<dim3(8, 8), 256, 0, stream>>>(ws + OFF_ADJ, ws + OFF_ADJ, ws + OFF_ADJ,
                                         ws + OFF_ADJ2, 512);
  k_splitB<<<dim3(16, 32), 256, 0, stream>>>(ws + OFF_ADJ, ws + OFF_ADJ2,
                                             (ushort_t*)(ws + OFF_BTHI),
                                             (ushort_t*)(ws + OFF_BTLO));
  k_start<<<832, 256, 0, stream>>>(IN, stW, stb, ws + OFF_X0);

  float* cur = ws + OFF_X0;
  float* nxt = ws + OFF_X1;
  ushort_t* UHI = (ushort_t*)(ws + OFF_UHI);
  ushort_t* ULO = (ushort_t*)(ws + OFF_ULO);
  int L = 13;
  const int dils[8] = {1, 2, 1, 2, 1, 2, 1, 2};
  for (int i = 0; i < 8; ++i) {
    int d = dils[i], Lo = L - d;
    k_gate<<<64 * Lo, 256, 0, stream>>>(cur, UHI, ULO, ws + OFF_SKIP,
                                        fW, fb, gW, gb, sW, sb, i, L, Lo, d);
    k_mfma<<<dim3(8, 4 * Lo), 256, 0, stream>>>(UHI, ULO,
                                                (ushort_t*)(ws + OFF_BTHI),
                                                (ushort_t*)(ws + OFF_BTLO),
                                                ws + OFF_Y);
    k_combine<<<64 * Lo, 256, 0, stream>>>(UHI, ULO, ws + OFF_Y, cur, nxt, ws,
                                           gcb, bng, bnb, bnm, bnv, i, L, Lo, d);
    float* tmp = cur; cur = nxt; nxt = tmp;
    L = Lo;
  }
  k_end<<<64, 256, 0, stream>>>(ws + OFF_SKIP, e1W, e1b, e2W, e2b, d_out, flag);
}